// Round 5
// baseline (1214.219 us; speedup 1.0000x reference)
//
#include <hip/hip_runtime.h>
#include <hip/hip_bf16.h>

// Problem constants: B=64, S=512, E=512, H=512, V=32000, T=2, L=1
// Output depends ONLY on batch sample 63 (lstm_out[-1] == last batch element).

#define NB 64   // persistent blocks for the recurrence

// LDS h-buffer swizzle: 32 groups of 16 floats, padded to stride 20 words.
#define HIDX(e) ((((e) >> 4) * 20) + ((e) & 15))

// ---------------------------------------------------------------------------
// Kernel 1: xg[t][g] = sum_e emb[sent[63][t]][e] * W_ih[g][e] + b_ih[g]+b_hh[g]
// M=512 (t), N=2048 (g), K=512. Epilogue writes BLOCK-LOCAL layout:
//   xg2[t*2048 + bb*32 + q*8 + jj]   where g = q*512 + bb*8 + jj
// so each lstm block reads one contiguous 128B line per step.
// ---------------------------------------------------------------------------
__global__ __launch_bounds__(256) void xg_gemm_k(
    const int* __restrict__ sent, const float* __restrict__ emb,
    const float* __restrict__ W_ih, const float* __restrict__ b_ih,
    const float* __restrict__ b_hh, float* __restrict__ xg)
{
    __shared__ float As[16][65];   // [k][m]
    __shared__ float Bs[16][65];   // [k][n]
    __shared__ int aidx[64];
    const int tid = threadIdx.x;
    const int t0 = blockIdx.x * 64;
    const int n0 = blockIdx.y * 64;
    if (tid < 64) aidx[tid] = sent[63 * 512 + t0 + tid];
    __syncthreads();

    const int kk = tid & 15;   // k within tile
    const int mm = tid >> 4;   // 0..15
    const int tx = tid & 15, ty = tid >> 4;
    float acc[4][4] = {};

    for (int kb = 0; kb < 512; kb += 16) {
        #pragma unroll
        for (int j = 0; j < 4; j++) {
            int m = mm + j * 16;
            As[kk][m] = emb[(size_t)aidx[m] * 512 + kb + kk];
            Bs[kk][m] = W_ih[(size_t)(n0 + m) * 512 + kb + kk];
        }
        __syncthreads();
        #pragma unroll
        for (int k = 0; k < 16; k++) {
            float a[4], bv[4];
            #pragma unroll
            for (int i = 0; i < 4; i++) a[i] = As[k][ty * 4 + i];
            #pragma unroll
            for (int j = 0; j < 4; j++) bv[j] = Bs[k][tx * 4 + j];
            #pragma unroll
            for (int i = 0; i < 4; i++)
                #pragma unroll
                for (int j = 0; j < 4; j++)
                    acc[i][j] += a[i] * bv[j];
        }
        __syncthreads();
    }

    #pragma unroll
    for (int i = 0; i < 4; i++) {
        int t = t0 + ty * 4 + i;
        #pragma unroll
        for (int j = 0; j < 4; j++) {
            int col = n0 + tx * 4 + j;
            int q = col >> 9, bb = (col >> 3) & 63, jj = col & 7;
            xg[(size_t)t * 2048 + bb * 32 + q * 8 + jj] =
                acc[i][j] + b_ih[col] + b_hh[col];
        }
    }
}

// ---------------------------------------------------------------------------
// Kernel 2: persistent batch-1 LSTM recurrence, 512 steps, 64 blocks x 256.
// Block b owns h-indices [b*8, b*8+8). Thread (cg = tid&31, rg = tid>>5)
// computes ALL FOUR gates of h-index j=rg over cols cg*16..+15; xor-butterfly
// over the 32 cg lanes gives every lane the full dot products; every lane
// runs the gate tail redundantly with c in a register. ONE barrier per step.
//
// Weights: the block's 32 W_hh rows (64 KB) are staged ONCE into LDS in a
// layout giving conflict-free ds_read_b64:
//   lw[(lr*8 + kp)*64 + cg*2 + e]  holds W_hh[row lr][col cg*16 + kp*2 + e]
// (lr = q*8 + j). R3/R4 proved the register allocator re-issues global weight
// loads every step (VGPR_Count=60, asm pin defeated) — LDS sidesteps it.
//
// Handoff: tagged 64-bit slots (tag=t+1 | float bits), relaxed agent-scope
// atomics to the LLC, ping-pong buffers by parity. No fences, no flags.
// Overwrite/restage safety: a wave passes the step-t+1 poll only after all
// blocks published step t, and publishing follows that wave's hbuf reads.
// ---------------------------------------------------------------------------
__global__ __launch_bounds__(256, 1) void lstm_seq_k(
    const float* __restrict__ h0, const float* __restrict__ c0,
    const float* __restrict__ W_hh, const float* __restrict__ xg,
    float* __restrict__ hs,
    unsigned long long* __restrict__ sA,
    unsigned long long* __restrict__ sB)
{
    __shared__ float lw[32 * 512];      // 64 KB weight slice
    __shared__ float hbuf[32 * 20];     // padded h staging

    const int tid = threadIdx.x;
    const int b = blockIdx.x;
    const int cg = tid & 31;
    const int rg = tid >> 5;            // this thread's h-index j = rg
    const int hidx = b * 8 + rg;        // global h index

    // --- one-time: stage this block's 32 W_hh rows into LDS ---
    {
        const int lr  = tid >> 3;       // local row 0..31  (lr = q*8 + jj)
        const int seg = tid & 7;        // 64-col segment
        const int q   = lr >> 3;
        const int jj  = lr & 7;
        const float* src = &W_hh[(size_t)(q * 512 + b * 8 + jj) * 512 + seg * 64];
        #pragma unroll
        for (int f = 0; f < 16; f++) {
            float4 v = *(const float4*)&src[f * 4];
            int c0i = seg * 64 + f * 4;
            float vv[4] = {v.x, v.y, v.z, v.w};
            #pragma unroll
            for (int e4 = 0; e4 < 4; e4++) {
                int c = c0i + e4;
                lw[(lr * 8 + ((c & 15) >> 1)) * 64 + (c >> 4) * 2 + (c & 1)] = vv[e4];
            }
        }
    }

    float creg = c0[63 * 512 + hidx];   // cell state, per-thread register
    __syncthreads();

    for (int t = 0; t < 512; t++) {
        // xg prefetch: 4 dwords in one 128B line per block (overlaps the poll).
        float xgp[4];
        #pragma unroll
        for (int q = 0; q < 4; q++)
            xgp[q] = xg[(size_t)t * 2048 + b * 32 + q * 8 + rg];

        if (t == 0) {
            hbuf[HIDX(tid)]       = h0[63 * 512 + tid];
            hbuf[HIDX(tid + 256)] = h0[63 * 512 + tid + 256];
        } else {
            unsigned long long* src = ((t - 1) & 1) ? sB : sA;
            const unsigned int expt = (unsigned int)t;
            unsigned long long v0, v1;
            for (;;) {
                v0 = __hip_atomic_load(&src[tid],       __ATOMIC_RELAXED, __HIP_MEMORY_SCOPE_AGENT);
                v1 = __hip_atomic_load(&src[tid + 256], __ATOMIC_RELAXED, __HIP_MEMORY_SCOPE_AGENT);
                if ((unsigned int)(v0 >> 32) == expt &&
                    (unsigned int)(v1 >> 32) == expt) break;
            }
            hbuf[HIDX(tid)]       = __uint_as_float((unsigned int)v0);
            hbuf[HIDX(tid + 256)] = __uint_as_float((unsigned int)v1);
        }
        __syncthreads();   // the ONLY barrier per step

        // h fragment: 16 consecutive h values from LDS.
        float hvf[16];
        #pragma unroll
        for (int i4 = 0; i4 < 4; i4++) {
            float4 v = *(const float4*)&hbuf[cg * 20 + i4 * 4];
            hvf[i4 * 4 + 0] = v.x; hvf[i4 * 4 + 1] = v.y;
            hvf[i4 * 4 + 2] = v.z; hvf[i4 * 4 + 3] = v.w;
        }

        // 4 gate rows x 16 cols; weights from LDS (8x ds_read_b64 per row,
        // conflict-free: lane stride 2 words).
        float acc[4];
        #pragma unroll
        for (int q = 0; q < 4; q++) {
            const float* wrow = &lw[((q * 8 + rg) * 8) * 64 + cg * 2];
            float s = 0.f;
            #pragma unroll
            for (int kp = 0; kp < 8; kp++) {
                float2 wv = *(const float2*)&wrow[kp * 64];
                s += wv.x * hvf[kp * 2 + 0];
                s += wv.y * hvf[kp * 2 + 1];
            }
            acc[q] = s;
        }

        // Butterfly over the 32 cg lanes -> every lane holds the full sums.
        #pragma unroll
        for (int q = 0; q < 4; q++) {
            #pragma unroll
            for (int m = 16; m >= 1; m >>= 1)
                acc[q] += __shfl_xor(acc[q], m, 64);
        }

        // Gate tail, computed redundantly by all 32 lanes of the rg group.
        // Torch gate order: i, f, g, o.
        float gi = acc[0] + xgp[0];
        float gf = acc[1] + xgp[1];
        float gg = acc[2] + xgp[2];
        float go = acc[3] + xgp[3];
        float ii = 1.f / (1.f + __expf(-gi));
        float ff = 1.f / (1.f + __expf(-gf));
        float cc = 1.f - 2.f / (__expf(2.f * gg) + 1.f);   // tanh
        float oo = 1.f / (1.f + __expf(-go));
        creg = ff * creg + ii * cc;
        float th = 1.f - 2.f / (__expf(2.f * creg) + 1.f); // tanh
        float hval = oo * th;

        if (cg == 0) {
            // History for the final linear (plain store, fire-and-forget).
            hs[(size_t)t * 512 + hidx] = hval;
            // Tagged slot: one 8B relaxed agent atomic store -> LLC.
            unsigned long long* dst = (t & 1) ? sB : sA;
            unsigned long long pv =
                ((unsigned long long)(unsigned int)(t + 1) << 32) |
                (unsigned long long)__float_as_uint(hval);
            __hip_atomic_store(&dst[hidx], pv,
                               __ATOMIC_RELAXED, __HIP_MEMORY_SCOPE_AGENT);
        }
    }
}

// ---------------------------------------------------------------------------
// Kernel 3: out[s][u] = hs[s] . W_lin[u] + b_lin[u], S=512, T=2.
// ---------------------------------------------------------------------------
__global__ __launch_bounds__(256) void final_linear_k(
    const float* __restrict__ hs, const float* __restrict__ W_lin,
    const float* __restrict__ b_lin, float* __restrict__ out)
{
    const int tid = threadIdx.x;
    const int wave = tid >> 6;
    const int lane = tid & 63;
    const int s = blockIdx.x * 4 + wave;
    const float* h = hs + (size_t)s * 512;
    float a0 = 0.f, a1 = 0.f;
    #pragma unroll
    for (int k0 = 0; k0 < 512; k0 += 64) {
        float hv = h[k0 + lane];
        a0 += hv * W_lin[k0 + lane];
        a1 += hv * W_lin[512 + k0 + lane];
    }
    #pragma unroll
    for (int m = 32; m >= 1; m >>= 1) {
        a0 += __shfl_xor(a0, m, 64);
        a1 += __shfl_xor(a1, m, 64);
    }
    if (lane == 0) {
        out[s * 2]     = a0 + b_lin[0];
        out[s * 2 + 1] = a1 + b_lin[1];
    }
}

// ---------------------------------------------------------------------------
extern "C" void kernel_launch(void* const* d_in, const int* in_sizes, int n_in,
                              void* d_out, int out_size, void* d_ws, size_t ws_size,
                              hipStream_t stream)
{
    const int*   sent  = (const int*)d_in[0];     // [64,512] int32
    const float* h0    = (const float*)d_in[1];   // [1,64,512]
    const float* c0    = (const float*)d_in[2];   // [1,64,512]
    const float* emb   = (const float*)d_in[3];   // [32000,512]
    const float* W_ih  = (const float*)d_in[4];   // [2048,512]
    const float* W_hh  = (const float*)d_in[5];   // [2048,512]
    const float* b_ih  = (const float*)d_in[6];   // [2048]
    const float* b_hh  = (const float*)d_in[7];   // [2048]
    const float* W_lin = (const float*)d_in[8];   // [2,512]
    const float* b_lin = (const float*)d_in[9];   // [2]
    float* out = (float*)d_out;                   // [512,2]

    char* ws = (char*)d_ws;
    float* xg = (float*)ws;                                   // 4 MB: [512,2048] (block-local layout)
    float* hs = (float*)(ws + 4 * 1024 * 1024);               // 1 MB: [512,512]
    unsigned long long* sA = (unsigned long long*)(ws + 5 * 1024 * 1024);          // 4 KB
    unsigned long long* sB = (unsigned long long*)(ws + 5 * 1024 * 1024 + 4096);   // 4 KB

    // Clear slot tags (0 != any expected tag 1..512).
    hipMemsetAsync(sA, 0, 2 * 4096, stream);

    dim3 g1(8, 32);
    xg_gemm_k<<<g1, 256, 0, stream>>>(sent, emb, W_ih, b_ih, b_hh, xg);
    lstm_seq_k<<<NB, 256, 0, stream>>>(h0, c0, W_hh, xg, hs, sA, sB);
    final_linear_k<<<128, 256, 0, stream>>>(hs, W_lin, b_lin, out);
}

// Round 6
// 1001.173 us; speedup vs baseline: 1.2128x; 1.2128x over previous
//
#include <hip/hip_runtime.h>
#include <hip/hip_bf16.h>

// Problem constants: B=64, S=512, E=512, H=512, V=32000, T=2, L=1
// Output depends ONLY on batch sample 63 (lstm_out[-1] == last batch element).

#define NB 64   // persistent blocks for the recurrence

// LDS h-buffer swizzle: 32 groups of 16 floats, padded to stride 20 words
// (80 B = 5*16 B -> float4 reads stay 16B-aligned).
#define HIDX(e) ((((e) >> 4) * 20) + ((e) & 15))

// ---------------------------------------------------------------------------
// Kernel 1: xg[t][g] = sum_e emb[sent[63][t]][e] * W_ih[g][e] + b_ih[g]+b_hh[g]
// M=512 (t), N=2048 (g), K=512. Epilogue writes BLOCK-LOCAL layout:
//   xg[t*2048 + bb*32 + q*8 + jj]   where g = q*512 + bb*8 + jj
// so each lstm block reads one contiguous 128B line per step.
// ---------------------------------------------------------------------------
__global__ __launch_bounds__(256) void xg_gemm_k(
    const int* __restrict__ sent, const float* __restrict__ emb,
    const float* __restrict__ W_ih, const float* __restrict__ b_ih,
    const float* __restrict__ b_hh, float* __restrict__ xg)
{
    __shared__ float As[16][65];   // [k][m]
    __shared__ float Bs[16][65];   // [k][n]
    __shared__ int aidx[64];
    const int tid = threadIdx.x;
    const int t0 = blockIdx.x * 64;
    const int n0 = blockIdx.y * 64;
    if (tid < 64) aidx[tid] = sent[63 * 512 + t0 + tid];
    __syncthreads();

    const int kk = tid & 15;   // k within tile
    const int mm = tid >> 4;   // 0..15
    const int tx = tid & 15, ty = tid >> 4;
    float acc[4][4] = {};

    for (int kb = 0; kb < 512; kb += 16) {
        #pragma unroll
        for (int j = 0; j < 4; j++) {
            int m = mm + j * 16;
            As[kk][m] = emb[(size_t)aidx[m] * 512 + kb + kk];
            Bs[kk][m] = W_ih[(size_t)(n0 + m) * 512 + kb + kk];
        }
        __syncthreads();
        #pragma unroll
        for (int k = 0; k < 16; k++) {
            float a[4], bv[4];
            #pragma unroll
            for (int i = 0; i < 4; i++) a[i] = As[k][ty * 4 + i];
            #pragma unroll
            for (int j = 0; j < 4; j++) bv[j] = Bs[k][tx * 4 + j];
            #pragma unroll
            for (int i = 0; i < 4; i++)
                #pragma unroll
                for (int j = 0; j < 4; j++)
                    acc[i][j] += a[i] * bv[j];
        }
        __syncthreads();
    }

    #pragma unroll
    for (int i = 0; i < 4; i++) {
        int t = t0 + ty * 4 + i;
        #pragma unroll
        for (int j = 0; j < 4; j++) {
            int col = n0 + tx * 4 + j;
            int q = col >> 9, bb = (col >> 3) & 63, jj = col & 7;
            xg[(size_t)t * 2048 + bb * 32 + q * 8 + jj] =
                acc[i][j] + b_ih[col] + b_hh[col];
        }
    }
}

// ---------------------------------------------------------------------------
// Kernel 2: persistent batch-1 LSTM recurrence, 512 steps, 64 blocks x 256.
// Block b owns h-indices [b*8, b*8+8). Thread (cg = tid&31, rg = tid>>5)
// computes ALL FOUR gates of h-index j=rg over cols cg*16..+15; xor-butterfly
// over the 32 cg lanes; every lane runs the gate tail redundantly with c in
// a register; cg==0 lanes publish. ONE barrier per step.
//
// Weights in LDS (64 KB), laid out for conflict-free ds_read_b128:
//   lw[(lr*4 + kq)*128 + cg*4 + e] = W_hh[row lr][col cg*16 + kq*4 + e]
// (lr = q*8 + j, row = q*512 + b*8 + j).
//
// R6 keys (from R5 post-mortem):
//  * Weight fragment (wv[4][4] float4 = 64 VGPRs) is ds_read BEFORE the poll
//    + compile-time memory barrier -> LDS traffic hides under the LLC wait
//    instead of sitting after __syncthreads on the critical path.
//  * hbuf double-buffered by step parity -> single barrier is race-free:
//    a wave can only reach step t+2 after ALL waves of ALL blocks passed
//    step t+1 (the poll covers all 512 tagged slots).
//  * s_sleep(1) backoff in the poll cuts LLC contention from 16K spinners.
//
// Handoff: tagged 64-bit slots (tag=t+1 | float bits), relaxed agent-scope
// atomics (LLC coherence point), ping-pong by parity. No fences.
// ---------------------------------------------------------------------------
__global__ __launch_bounds__(256, 1) void lstm_seq_k(
    const float* __restrict__ h0, const float* __restrict__ c0,
    const float* __restrict__ W_hh, const float* __restrict__ xg,
    float* __restrict__ hs,
    unsigned long long* __restrict__ sA,
    unsigned long long* __restrict__ sB)
{
    __shared__ float lw[32 * 512];      // 64 KB weight slice
    __shared__ float hbufA[32 * 20];    // h staging, parity 0
    __shared__ float hbufB[32 * 20];    // h staging, parity 1

    const int tid = threadIdx.x;
    const int b = blockIdx.x;
    const int cg = tid & 31;
    const int rg = tid >> 5;            // this thread's h-index j = rg
    const int hidx = b * 8 + rg;        // global h index

    // --- one-time: stage this block's 32 W_hh rows into LDS ---
    {
        const int lr  = tid >> 3;       // local row 0..31  (lr = q*8 + jj)
        const int seg = tid & 7;        // 64-col segment
        const int q   = lr >> 3;
        const int jj  = lr & 7;
        const float* src = &W_hh[(size_t)(q * 512 + b * 8 + jj) * 512 + seg * 64];
        #pragma unroll
        for (int f = 0; f < 16; f++) {
            float4 v = *(const float4*)&src[f * 4];
            int c0i = seg * 64 + f * 4;
            int kq  = (c0i & 15) >> 2;
            int cg4 = (c0i >> 4) * 4;
            *(float4*)&lw[(size_t)(lr * 4 + kq) * 128 + cg4] = v;
        }
    }

    float creg = c0[63 * 512 + hidx];   // cell state, per-thread register
    __syncthreads();

    for (int t = 0; t < 512; t++) {
        float* hb = (t & 1) ? hbufB : hbufA;

        // ---- weight fragment prefetch: 16x ds_read_b128, BEFORE the poll ----
        float4 wv[4][4];
        #pragma unroll
        for (int q = 0; q < 4; q++) {
            const float* wrow = &lw[(size_t)((q * 8 + rg) * 4) * 128 + cg * 4];
            #pragma unroll
            for (int kq = 0; kq < 4; kq++)
                wv[q][kq] = *(const float4*)&wrow[kq * 128];
        }
        // xg prefetch (one 128B line per block; overlaps the wait too).
        float xgp[4];
        #pragma unroll
        for (int q = 0; q < 4; q++)
            xgp[q] = xg[(size_t)t * 2048 + b * 32 + q * 8 + rg];

        // Keep the loads above issued before the poll (no sinking).
        asm volatile("" ::: "memory");

        if (t == 0) {
            hb[HIDX(tid)]       = h0[63 * 512 + tid];
            hb[HIDX(tid + 256)] = h0[63 * 512 + tid + 256];
        } else {
            unsigned long long* src = ((t - 1) & 1) ? sB : sA;
            const unsigned int expt = (unsigned int)t;
            unsigned long long v0, v1;
            for (;;) {
                v0 = __hip_atomic_load(&src[tid],       __ATOMIC_RELAXED, __HIP_MEMORY_SCOPE_AGENT);
                v1 = __hip_atomic_load(&src[tid + 256], __ATOMIC_RELAXED, __HIP_MEMORY_SCOPE_AGENT);
                if ((unsigned int)(v0 >> 32) == expt &&
                    (unsigned int)(v1 >> 32) == expt) break;
                __builtin_amdgcn_s_sleep(1);   // backoff: cut LLC contention
            }
            hb[HIDX(tid)]       = __uint_as_float((unsigned int)v0);
            hb[HIDX(tid + 256)] = __uint_as_float((unsigned int)v1);
        }
        __syncthreads();   // the ONLY barrier per step (hbuf is double-buffered)

        // h fragment: 16 consecutive h values from LDS.
        float hvf[16];
        #pragma unroll
        for (int i4 = 0; i4 < 4; i4++) {
            float4 v = *(const float4*)&hb[cg * 20 + i4 * 4];
            hvf[i4 * 4 + 0] = v.x; hvf[i4 * 4 + 1] = v.y;
            hvf[i4 * 4 + 2] = v.z; hvf[i4 * 4 + 3] = v.w;
        }

        // 4 gate rows x 16 cols, weights already in registers.
        float acc[4];
        #pragma unroll
        for (int q = 0; q < 4; q++) {
            float s = 0.f;
            #pragma unroll
            for (int kq = 0; kq < 4; kq++) {
                s += wv[q][kq].x * hvf[kq * 4 + 0];
                s += wv[q][kq].y * hvf[kq * 4 + 1];
                s += wv[q][kq].z * hvf[kq * 4 + 2];
                s += wv[q][kq].w * hvf[kq * 4 + 3];
            }
            acc[q] = s;
        }

        // Butterfly over the 32 cg lanes (xor masks <=16 stay within rg half).
        #pragma unroll
        for (int q = 0; q < 4; q++) {
            #pragma unroll
            for (int m = 16; m >= 1; m >>= 1)
                acc[q] += __shfl_xor(acc[q], m, 64);
        }

        // Gate tail, redundantly on all 32 lanes. Torch order: i, f, g, o.
        float gi = acc[0] + xgp[0];
        float gf = acc[1] + xgp[1];
        float gg = acc[2] + xgp[2];
        float go = acc[3] + xgp[3];
        float ii = 1.f / (1.f + __expf(-gi));
        float ff = 1.f / (1.f + __expf(-gf));
        float cc = 1.f - 2.f / (__expf(2.f * gg) + 1.f);   // tanh
        float oo = 1.f / (1.f + __expf(-go));
        creg = ff * creg + ii * cc;
        float th = 1.f - 2.f / (__expf(2.f * creg) + 1.f); // tanh
        float hval = oo * th;

        if (cg == 0) {
            // History for the final linear (plain store, fire-and-forget).
            hs[(size_t)t * 512 + hidx] = hval;
            // Tagged slot: one 8B relaxed agent atomic store -> LLC.
            unsigned long long* dst = (t & 1) ? sB : sA;
            unsigned long long pv =
                ((unsigned long long)(unsigned int)(t + 1) << 32) |
                (unsigned long long)__float_as_uint(hval);
            __hip_atomic_store(&dst[hidx], pv,
                               __ATOMIC_RELAXED, __HIP_MEMORY_SCOPE_AGENT);
        }
    }
}

// ---------------------------------------------------------------------------
// Kernel 3: out[s][u] = hs[s] . W_lin[u] + b_lin[u], S=512, T=2.
// ---------------------------------------------------------------------------
__global__ __launch_bounds__(256) void final_linear_k(
    const float* __restrict__ hs, const float* __restrict__ W_lin,
    const float* __restrict__ b_lin, float* __restrict__ out)
{
    const int tid = threadIdx.x;
    const int wave = tid >> 6;
    const int lane = tid & 63;
    const int s = blockIdx.x * 4 + wave;
    const float* h = hs + (size_t)s * 512;
    float a0 = 0.f, a1 = 0.f;
    #pragma unroll
    for (int k0 = 0; k0 < 512; k0 += 64) {
        float hv = h[k0 + lane];
        a0 += hv * W_lin[k0 + lane];
        a1 += hv * W_lin[512 + k0 + lane];
    }
    #pragma unroll
    for (int m = 32; m >= 1; m >>= 1) {
        a0 += __shfl_xor(a0, m, 64);
        a1 += __shfl_xor(a1, m, 64);
    }
    if (lane == 0) {
        out[s * 2]     = a0 + b_lin[0];
        out[s * 2 + 1] = a1 + b_lin[1];
    }
}

// ---------------------------------------------------------------------------
extern "C" void kernel_launch(void* const* d_in, const int* in_sizes, int n_in,
                              void* d_out, int out_size, void* d_ws, size_t ws_size,
                              hipStream_t stream)
{
    const int*   sent  = (const int*)d_in[0];     // [64,512] int32
    const float* h0    = (const float*)d_in[1];   // [1,64,512]
    const float* c0    = (const float*)d_in[2];   // [1,64,512]
    const float* emb   = (const float*)d_in[3];   // [32000,512]
    const float* W_ih  = (const float*)d_in[4];   // [2048,512]
    const float* W_hh  = (const float*)d_in[5];   // [2048,512]
    const float* b_ih  = (const float*)d_in[6];   // [2048]
    const float* b_hh  = (const float*)d_in[7];   // [2048]
    const float* W_lin = (const float*)d_in[8];   // [2,512]
    const float* b_lin = (const float*)d_in[9];   // [2]
    float* out = (float*)d_out;                   // [512,2]

    char* ws = (char*)d_ws;
    float* xg = (float*)ws;                                   // 4 MB: [512,2048] (block-local layout)
    float* hs = (float*)(ws + 4 * 1024 * 1024);               // 1 MB: [512,512]
    unsigned long long* sA = (unsigned long long*)(ws + 5 * 1024 * 1024);          // 4 KB
    unsigned long long* sB = (unsigned long long*)(ws + 5 * 1024 * 1024 + 4096);   // 4 KB

    // Clear slot tags (0 != any expected tag 1..512).
    hipMemsetAsync(sA, 0, 2 * 4096, stream);

    dim3 g1(8, 32);
    xg_gemm_k<<<g1, 256, 0, stream>>>(sent, emb, W_ih, b_ih, b_hh, xg);
    lstm_seq_k<<<NB, 256, 0, stream>>>(h0, c0, W_hh, xg, hs, sA, sB);
    final_linear_k<<<128, 256, 0, stream>>>(hs, W_lin, b_lin, out);
}